// Round 1
// baseline (984.898 us; speedup 1.0000x reference)
//
#include <hip/hip_runtime.h>
#include <math.h>

// ---- problem constants ----
constexpr int BB = 2;          // batch
constexpr int NN = 2048;       // seq len
constexpr int DM = 1024;       // model dim
constexpr int NH = 16;         // heads
constexpr int HD = 64;         // head dim
constexpr int DI = NH * HD;    // inner dim = 1024
constexpr int MT = BB * NN;    // 4096 tokens
constexpr float ATTN_SCALE = 0.125f;  // 64^-0.5

union F4 { float4 v; float a[4]; };

// ---------------- RMSNorm: x = tokens * rsqrt(mean(tokens^2)+eps) * w ----------------
__global__ __launch_bounds__(256) void k_rmsnorm(const float* __restrict__ tokens,
                                                 const float* __restrict__ w,
                                                 float* __restrict__ x) {
  const int tok = blockIdx.x;
  const int t = threadIdx.x;
  float4 v = ((const float4*)(tokens + (size_t)tok * DM))[t];
  float ss = v.x * v.x + v.y * v.y + v.z * v.z + v.w * v.w;
#pragma unroll
  for (int m = 1; m < 64; m <<= 1) ss += __shfl_xor(ss, m, 64);
  __shared__ float red[4];
  if ((t & 63) == 0) red[t >> 6] = ss;
  __syncthreads();
  float tot = red[0] + red[1] + red[2] + red[3];
  float inv = rsqrtf(tot * (1.0f / DM) + 1.1920929e-7f);
  float4 wv = ((const float4*)w)[t];
  float4 o;
  o.x = v.x * inv * wv.x;
  o.y = v.y * inv * wv.y;
  o.z = v.z * inv * wv.z;
  o.w = v.w * inv * wv.w;
  ((float4*)(x + (size_t)tok * DM))[t] = o;
}

// ---------------- fp32 tiled GEMM: C[MT][Ncols] = A[MT][1024] @ B[1024][Ncols] ----------------
// 64x64 tile, BK=16, 256 threads, 4x4 micro-tile per thread.
__global__ __launch_bounds__(256) void k_gemm(const float* __restrict__ A,
                                              const float* __restrict__ Bm,
                                              float* __restrict__ C, int Ncols) {
  __shared__ float As[16][68];  // [k][m], pad 68 -> conflict-free frag reads
  __shared__ float Bs[16][64];  // [k][n]
  const int t = threadIdx.x;
  const int tx = t & 15, ty = t >> 4;
  const int bm = blockIdx.y, bn = blockIdx.x;
  const int arow = t >> 2;          // 0..63
  const int akq = (t & 3) << 2;     // k-quad 0,4,8,12
  const int brow = t >> 4;          // 0..15
  const int bcol = (t & 15) << 2;   // 0..60
  const float* Ap = A + (size_t)(bm * 64 + arow) * DM + akq;
  const float* Bp = Bm + (size_t)brow * Ncols + (size_t)bn * 64 + bcol;
  float acc[4][4] = {};
  for (int k0 = 0; k0 < DM; k0 += 16) {
    float4 a4 = *(const float4*)(Ap + k0);
    float4 b4 = *(const float4*)(Bp + (size_t)k0 * Ncols);
    __syncthreads();
    As[akq + 0][arow] = a4.x;
    As[akq + 1][arow] = a4.y;
    As[akq + 2][arow] = a4.z;
    As[akq + 3][arow] = a4.w;
    *(float4*)&Bs[brow][bcol] = b4;
    __syncthreads();
#pragma unroll
    for (int kk = 0; kk < 16; kk++) {
      F4 av, bv;
      av.v = *(const float4*)&As[kk][ty << 2];
      bv.v = *(const float4*)&Bs[kk][tx << 2];
#pragma unroll
      for (int i = 0; i < 4; i++)
#pragma unroll
        for (int j = 0; j < 4; j++)
          acc[i][j] = fmaf(av.a[i], bv.a[j], acc[i][j]);
    }
  }
  float* Cp = C + (size_t)(bm * 64 + (ty << 2)) * Ncols + (size_t)bn * 64 + (tx << 2);
#pragma unroll
  for (int i = 0; i < 4; i++) {
    float4 o = make_float4(acc[i][0], acc[i][1], acc[i][2], acc[i][3]);
    *(float4*)(Cp + (size_t)i * Ncols) = o;
  }
}

// ---------------- gates = sigmoid(x @ Wg), Wg[1024][16] ----------------
__global__ __launch_bounds__(256) void k_gates(const float* __restrict__ x,
                                               const float* __restrict__ Wg,
                                               float* __restrict__ g) {
  const int tok = blockIdx.x * 16 + (threadIdx.x >> 4);
  const int h = threadIdx.x & 15;
  const float* xr = x + (size_t)tok * DM;
  float s = 0.f;
  for (int k = 0; k < DM; k += 4) {
    float4 xv = *(const float4*)(xr + k);
    s += xv.x * Wg[(k + 0) * NH + h];
    s += xv.y * Wg[(k + 1) * NH + h];
    s += xv.z * Wg[(k + 2) * NH + h];
    s += xv.w * Wg[(k + 3) * NH + h];
  }
  g[(size_t)tok * NH + h] = 1.f / (1.f + __expf(-s));
}

// ---------------- flash-style causal attention + gate, in-place over q ----------------
// grid: x = qtile (N/32 = 64), y = b*NH + h (32). block = 256 (16x16).
// Each thread: 2 q-rows x {4 score-cols (tx+16j)} / {4 d-cols (4tx+j)}.
__global__ __launch_bounds__(256) void k_attn(const float* __restrict__ q,
                                              const float* __restrict__ kv,
                                              const float* __restrict__ gates,
                                              float* __restrict__ out) {
  __shared__ float Qs[32][68];
  __shared__ float Ks[64][68];
  __shared__ float Vs[64][68];
  __shared__ float Ps[32][68];
  const int qt = blockIdx.x;
  const int bh = blockIdx.y;
  const int b = bh >> 4, h = bh & 15;
  const int t = threadIdx.x;
  const int tx = t & 15, ty = t >> 4;

  // load Q tile [32][64]
  const float* qbase = q + ((size_t)(b * NN + qt * 32)) * DI + h * HD;
#pragma unroll
  for (int i = 0; i < 2; i++) {
    int lin = i * 1024 + t * 4;
    int r = lin >> 6, c = lin & 63;
    *(float4*)&Qs[r][c] = *(const float4*)(qbase + (size_t)r * DI + c);
  }

  float m_run[2] = {-1e30f, -1e30f};
  float l_run[2] = {0.f, 0.f};
  float accO[2][4] = {};

  const int ntiles = (qt >> 1) + 1;
  for (int kt = 0; kt < ntiles; kt++) {
    __syncthreads();  // previous tile's Ks/Vs/Ps reads complete
    const float* kbase = kv + ((size_t)(b * NN + kt * 64)) * (2 * DI) + h * HD;
    const float* vbase = kbase + DI;
#pragma unroll
    for (int i = 0; i < 4; i++) {
      int lin = i * 1024 + t * 4;
      int r = lin >> 6, c = lin & 63;
      *(float4*)&Ks[r][c] = *(const float4*)(kbase + (size_t)r * (2 * DI) + c);
      *(float4*)&Vs[r][c] = *(const float4*)(vbase + (size_t)r * (2 * DI) + c);
    }
    __syncthreads();

    // S = Q K^T  (cols mapped tx+16j to spread LDS banks)
    float s[2][4] = {};
#pragma unroll
    for (int dd = 0; dd < 64; dd += 4) {
      F4 qv0, qv1, kvv[4];
      qv0.v = *(const float4*)&Qs[2 * ty + 0][dd];
      qv1.v = *(const float4*)&Qs[2 * ty + 1][dd];
#pragma unroll
      for (int j = 0; j < 4; j++) kvv[j].v = *(const float4*)&Ks[tx + 16 * j][dd];
#pragma unroll
      for (int j = 0; j < 4; j++)
#pragma unroll
        for (int u = 0; u < 4; u++) {
          s[0][j] = fmaf(qv0.a[u], kvv[j].a[u], s[0][j]);
          s[1][j] = fmaf(qv1.a[u], kvv[j].a[u], s[1][j]);
        }
    }
    const bool diag = (kt == ntiles - 1);
#pragma unroll
    for (int i = 0; i < 2; i++) {
      int rowg = qt * 32 + 2 * ty + i;
#pragma unroll
      for (int j = 0; j < 4; j++) {
        s[i][j] *= ATTN_SCALE;
        if (diag) {
          int colg = kt * 64 + tx + 16 * j;
          if (colg > rowg) s[i][j] = -1e30f;
        }
      }
    }

    // online softmax per q-row (row group = 16 lanes sharing ty)
#pragma unroll
    for (int i = 0; i < 2; i++) {
      float mx = fmaxf(fmaxf(s[i][0], s[i][1]), fmaxf(s[i][2], s[i][3]));
#pragma unroll
      for (int mk = 1; mk < 16; mk <<= 1) mx = fmaxf(mx, __shfl_xor(mx, mk, 64));
      float mnew = fmaxf(m_run[i], mx);
      float cf = __expf(m_run[i] - mnew);
      float rs = 0.f;
      float p[4];
#pragma unroll
      for (int j = 0; j < 4; j++) {
        p[j] = __expf(s[i][j] - mnew);
        rs += p[j];
      }
#pragma unroll
      for (int mk = 1; mk < 16; mk <<= 1) rs += __shfl_xor(rs, mk, 64);
      l_run[i] = l_run[i] * cf + rs;
      m_run[i] = mnew;
#pragma unroll
      for (int j = 0; j < 4; j++) accO[i][j] *= cf;
#pragma unroll
      for (int j = 0; j < 4; j++) Ps[2 * ty + i][tx + 16 * j] = p[j];
    }
    __syncthreads();

    // accO += P @ V  (d cols = 4tx+j)
#pragma unroll
    for (int kk = 0; kk < 64; kk += 4) {
      F4 p0, p1, vv[4];
      p0.v = *(const float4*)&Ps[2 * ty + 0][kk];
      p1.v = *(const float4*)&Ps[2 * ty + 1][kk];
#pragma unroll
      for (int u = 0; u < 4; u++) vv[u].v = *(const float4*)&Vs[kk + u][tx << 2];
#pragma unroll
      for (int u = 0; u < 4; u++)
#pragma unroll
        for (int j = 0; j < 4; j++) {
          accO[0][j] = fmaf(p0.a[u], vv[u].a[j], accO[0][j]);
          accO[1][j] = fmaf(p1.a[u], vv[u].a[j], accO[1][j]);
        }
    }
  }

  // epilogue: normalize, gate, write (same rows/cols this block read from q)
#pragma unroll
  for (int i = 0; i < 2; i++) {
    int row = qt * 32 + 2 * ty + i;
    float gate = gates[((size_t)b * NN + row) * NH + h];
    float invl = gate / l_run[i];
    float4 o = make_float4(accO[i][0] * invl, accO[i][1] * invl,
                           accO[i][2] * invl, accO[i][3] * invl);
    *(float4*)(out + ((size_t)(b * NN + row)) * DI + h * HD + (tx << 2)) = o;
  }
}

extern "C" void kernel_launch(void* const* d_in, const int* in_sizes, int n_in,
                              void* d_out, int out_size, void* d_ws, size_t ws_size,
                              hipStream_t stream) {
  const float* tokens = (const float*)d_in[0];
  const float* norm_w = (const float*)d_in[1];
  const float* Wq     = (const float*)d_in[2];
  const float* Wkv    = (const float*)d_in[3];
  const float* Wout   = (const float*)d_in[4];
  const float* Wg     = (const float*)d_in[5];
  float* out = (float*)d_out;

  float* ws  = (float*)d_ws;
  float* x   = ws;                              // [4096][1024]
  float* qb  = x + (size_t)MT * DM;             // [4096][1024] (q, then gated attn out in-place)
  float* kvb = qb + (size_t)MT * DI;            // [4096][2048]
  float* gb  = kvb + (size_t)MT * 2 * DI;       // [4096][16]

  k_rmsnorm<<<MT, 256, 0, stream>>>(tokens, norm_w, x);
  k_gemm<<<dim3(DI / 64, MT / 64), 256, 0, stream>>>(x, Wq, qb, DI);
  k_gemm<<<dim3(2 * DI / 64, MT / 64), 256, 0, stream>>>(x, Wkv, kvb, 2 * DI);
  k_gates<<<MT / 16, 256, 0, stream>>>(x, Wg, gb);
  k_attn<<<dim3(NN / 32, BB * NH), 256, 0, stream>>>(qb, kvb, gb, qb);
  k_gemm<<<dim3(DM / 64, MT / 64), 256, 0, stream>>>(qb, Wout, out, DM);
}

// Round 2
// 731.736 us; speedup vs baseline: 1.3460x; 1.3460x over previous
//
#include <hip/hip_runtime.h>
#include <hip/hip_bf16.h>
#include <math.h>

// ---- problem constants ----
constexpr int BB = 2;          // batch
constexpr int NN = 2048;       // seq len
constexpr int DM = 1024;       // model dim
constexpr int NH = 16;         // heads
constexpr int HD = 64;         // head dim
constexpr int DI = NH * HD;    // inner dim = 1024
constexpr int MT = BB * NN;    // 4096 tokens
constexpr float SM_SCALE = 0.125f * 1.44269504089f;  // 64^-0.5 * log2(e)

typedef __attribute__((ext_vector_type(8))) short short8v;  // 8 bf16 (4 VGPRs)
typedef __attribute__((ext_vector_type(4))) float f32x4;    // MFMA C/D

union F4 { float4 v; float a[4]; };

__device__ inline unsigned cvt_pk_bf16(float lo, float hi) {
  unsigned r;
  asm("v_cvt_pk_bf16_f32 %0, %1, %2" : "=v"(r) : "v"(lo), "v"(hi));
  return r;
}
__device__ inline void pl32_swap(unsigned& a, unsigned& b) {
  asm("v_permlane32_swap_b32 %0, %1" : "+v"(a), "+v"(b));
}
__device__ inline void pl16_swap(unsigned& a, unsigned& b) {
  asm("v_permlane16_swap_b32 %0, %1" : "+v"(a), "+v"(b));
}

// ---------------- RMSNorm ----------------
__global__ __launch_bounds__(256) void k_rmsnorm(const float* __restrict__ tokens,
                                                 const float* __restrict__ w,
                                                 float* __restrict__ x) {
  const int tok = blockIdx.x;
  const int t = threadIdx.x;
  float4 v = ((const float4*)(tokens + (size_t)tok * DM))[t];
  float ss = v.x * v.x + v.y * v.y + v.z * v.z + v.w * v.w;
#pragma unroll
  for (int m = 1; m < 64; m <<= 1) ss += __shfl_xor(ss, m, 64);
  __shared__ float red[4];
  if ((t & 63) == 0) red[t >> 6] = ss;
  __syncthreads();
  float tot = red[0] + red[1] + red[2] + red[3];
  float inv = rsqrtf(tot * (1.0f / DM) + 1.1920929e-7f);
  float4 wv = ((const float4*)w)[t];
  float4 o;
  o.x = v.x * inv * wv.x;
  o.y = v.y * inv * wv.y;
  o.z = v.z * inv * wv.z;
  o.w = v.w * inv * wv.w;
  ((float4*)(x + (size_t)tok * DM))[t] = o;
}

// ---------------- fp32 tiled GEMM with selectable epilogue ----------------
// MODE 0: fp32 C.  MODE 1: bf16 [b,h,n,d] into OK.  MODE 2: cols<DI -> K like
// MODE1; cols>=DI -> bf16 transposed [b,h,d,n] into OV.
template <int MODE>
__global__ __launch_bounds__(256) void k_gemm_t(const float* __restrict__ A,
                                                const float* __restrict__ Bm,
                                                float* __restrict__ C,
                                                __hip_bfloat16* __restrict__ OK,
                                                __hip_bfloat16* __restrict__ OV,
                                                int Ncols) {
  __shared__ float As[16][68];
  __shared__ float Bs[16][64];
  const int t = threadIdx.x;
  const int tx = t & 15, ty = t >> 4;
  const int bm = blockIdx.y, bn = blockIdx.x;
  const int arow = t >> 2;
  const int akq = (t & 3) << 2;
  const int brow = t >> 4;
  const int bcol = (t & 15) << 2;
  const float* Ap = A + (size_t)(bm * 64 + arow) * DM + akq;
  const float* Bp = Bm + (size_t)brow * Ncols + (size_t)bn * 64 + bcol;
  float acc[4][4] = {};
  for (int k0 = 0; k0 < DM; k0 += 16) {
    float4 a4 = *(const float4*)(Ap + k0);
    float4 b4 = *(const float4*)(Bp + (size_t)k0 * Ncols);
    __syncthreads();
    As[akq + 0][arow] = a4.x;
    As[akq + 1][arow] = a4.y;
    As[akq + 2][arow] = a4.z;
    As[akq + 3][arow] = a4.w;
    *(float4*)&Bs[brow][bcol] = b4;
    __syncthreads();
#pragma unroll
    for (int kk = 0; kk < 16; kk++) {
      F4 av, bv;
      av.v = *(const float4*)&As[kk][ty << 2];
      bv.v = *(const float4*)&Bs[kk][tx << 2];
#pragma unroll
      for (int i = 0; i < 4; i++)
#pragma unroll
        for (int j = 0; j < 4; j++)
          acc[i][j] = fmaf(av.a[i], bv.a[j], acc[i][j]);
    }
  }
  const int row0 = bm * 64 + (ty << 2);
  const int col0 = bn * 64 + (tx << 2);
  if (MODE == 0) {
    float* Cp = C + (size_t)row0 * Ncols + col0;
#pragma unroll
    for (int i = 0; i < 4; i++)
      *(float4*)(Cp + (size_t)i * Ncols) =
          make_float4(acc[i][0], acc[i][1], acc[i][2], acc[i][3]);
  } else if (MODE == 1 || (MODE == 2 && col0 < DI)) {
    const int b = row0 >> 11, n0 = row0 & (NN - 1);
    const int h = (col0 & (DI - 1)) >> 6, d = col0 & 63;
    __hip_bfloat16* dst = OK + ((size_t)(b * NH + h) * NN + n0) * HD + d;
#pragma unroll
    for (int i = 0; i < 4; i++) {
      uint2 pk = make_uint2(cvt_pk_bf16(acc[i][0], acc[i][1]),
                            cvt_pk_bf16(acc[i][2], acc[i][3]));
      *(uint2*)(dst + (size_t)i * HD) = pk;
    }
  } else {  // V transposed
    const int c = col0 - DI;
    const int b = row0 >> 11, n0 = row0 & (NN - 1);
    const int h = c >> 6, d0 = c & 63;
    __hip_bfloat16* dst = OV + ((size_t)(b * NH + h) * HD + d0) * NN + n0;
#pragma unroll
    for (int j = 0; j < 4; j++) {
      uint2 pk = make_uint2(cvt_pk_bf16(acc[0][j], acc[1][j]),
                            cvt_pk_bf16(acc[2][j], acc[3][j]));
      *(uint2*)(dst + (size_t)j * NN) = pk;
    }
  }
}

// ---------------- gates = sigmoid(x @ Wg) ----------------
__global__ __launch_bounds__(256) void k_gates(const float* __restrict__ x,
                                               const float* __restrict__ Wg,
                                               float* __restrict__ g) {
  const int tok = blockIdx.x * 16 + (threadIdx.x >> 4);
  const int h = threadIdx.x & 15;
  const float* xr = x + (size_t)tok * DM;
  float s = 0.f;
  for (int k = 0; k < DM; k += 4) {
    float4 xv = *(const float4*)(xr + k);
    s += xv.x * Wg[(k + 0) * NH + h];
    s += xv.y * Wg[(k + 1) * NH + h];
    s += xv.z * Wg[(k + 2) * NH + h];
    s += xv.w * Wg[(k + 3) * NH + h];
  }
  g[(size_t)tok * NH + h] = 1.f / (1.f + __expf(-s));
}

// ---------------- bf16 MFMA flash attention (swapped operands, no main-loop LDS) ----
// grid: x = 32 qtiles of 64 rows (reversed for causal balance), y = b*NH+h.
// block = 256 = 4 waves; each wave owns 16 q rows. S^T = mfma(K, Q^T); P
// redistributed in-register (cvt_pk + permlane32/16_swap) into PV B-frags;
// O^T = mfma(Vt, P^T). Gate + 1/l fused; LDS only for the output transpose.
__global__ __launch_bounds__(256) void k_attn_mfma(const __hip_bfloat16* __restrict__ Qb,
                                                   const __hip_bfloat16* __restrict__ Kb,
                                                   const __hip_bfloat16* __restrict__ Vtb,
                                                   const float* __restrict__ gates,
                                                   float* __restrict__ ao) {
  const int bh = blockIdx.y;
  const int qt = (int)gridDim.x - 1 - (int)blockIdx.x;  // heavy tiles dispatch first
  const int wid = threadIdx.x >> 6;
  const int lane = threadIdx.x & 63;
  const int lg = lane >> 4, lq = lane & 15;
  const int q0 = qt * 64 + wid * 16;

  const __hip_bfloat16* Qh = Qb + (size_t)bh * NN * HD;
  const __hip_bfloat16* Kh = Kb + (size_t)bh * NN * HD;
  const __hip_bfloat16* Vh = Vtb + (size_t)bh * HD * NN;

  short8v qf[2];
#pragma unroll
  for (int ks = 0; ks < 2; ks++)
    qf[ks] = *(const short8v*)(Qh + (size_t)(q0 + lq) * HD + ks * 32 + lg * 8);

  f32x4 oacc[4];
#pragma unroll
  for (int j = 0; j < 4; j++) oacc[j] = (f32x4){0.f, 0.f, 0.f, 0.f};
  float m_run = -3.0e38f, l_run = 0.f;

  const int ntiles = qt + 1;
  for (int kt = 0; kt < ntiles; kt++) {
    const int kvb = kt * 64;
    short8v kf[4][2], vf[4][2];
#pragma unroll
    for (int j = 0; j < 4; j++)
#pragma unroll
      for (int ks = 0; ks < 2; ks++)
        kf[j][ks] = *(const short8v*)(Kh + (size_t)(kvb + j * 16 + lq) * HD + ks * 32 + lg * 8);
#pragma unroll
    for (int j = 0; j < 4; j++)
#pragma unroll
      for (int ks = 0; ks < 2; ks++)
        vf[j][ks] = *(const short8v*)(Vh + (size_t)(j * 16 + lq) * NN + kvb + ks * 32 + lg * 8);

    f32x4 sacc[4];
#pragma unroll
    for (int j = 0; j < 4; j++) sacc[j] = (f32x4){0.f, 0.f, 0.f, 0.f};
#pragma unroll
    for (int j = 0; j < 4; j++)
#pragma unroll
      for (int ks = 0; ks < 2; ks++)
        sacc[j] = __builtin_amdgcn_mfma_f32_16x16x32_bf16(kf[j][ks], qf[ks], sacc[j], 0, 0, 0);

    // scale + causal mask (only the diagonal tile can have kv > q)
    const int qg = q0 + lq;
    const bool diag = (kt == ntiles - 1);
    float ss[4][4];
#pragma unroll
    for (int j = 0; j < 4; j++)
#pragma unroll
      for (int r = 0; r < 4; r++) {
        float v = sacc[j][r] * SM_SCALE;
        if (diag && (kvb + j * 16 + lg * 4 + r > qg)) v = -3.0e38f;
        ss[j][r] = v;
      }

    // online softmax: each lane owns one q column; row spans 4 lane-groups
    float tmax = -3.0e38f;
#pragma unroll
    for (int j = 0; j < 4; j++)
#pragma unroll
      for (int r = 0; r < 4; r++) tmax = fmaxf(tmax, ss[j][r]);
    tmax = fmaxf(tmax, __shfl_xor(tmax, 16));
    tmax = fmaxf(tmax, __shfl_xor(tmax, 32));
    const float mnew = fmaxf(m_run, tmax);
    const float cf = exp2f(m_run - mnew);
    float psum = 0.f;
    unsigned upk[4], vpk[4];
#pragma unroll
    for (int j = 0; j < 4; j++) {
      float p0 = exp2f(ss[j][0] - mnew), p1 = exp2f(ss[j][1] - mnew);
      float p2 = exp2f(ss[j][2] - mnew), p3 = exp2f(ss[j][3] - mnew);
      psum += (p0 + p1) + (p2 + p3);
      upk[j] = cvt_pk_bf16(p0, p1);
      vpk[j] = cvt_pk_bf16(p2, p3);
    }
    psum += __shfl_xor(psum, 16);
    psum += __shfl_xor(psum, 32);
    l_run = l_run * cf + psum;
    m_run = mnew;
#pragma unroll
    for (int j = 0; j < 4; j++)
#pragma unroll
      for (int r = 0; r < 4; r++) oacc[j][r] *= cf;

    // PV: B-frag words by lane-group g: [uA@gg0,uA@gg2,uC@gg0,uC@gg2] etc.
    // = dst/src outputs of permlane16_swap(permlane32_swap(u_{2ks}, u_{2ks+1}))
#pragma unroll
    for (int ks = 0; ks < 2; ks++) {
      unsigned w0 = upk[2 * ks], w2 = upk[2 * ks + 1];
      unsigned w1 = vpk[2 * ks], w3 = vpk[2 * ks + 1];
      pl32_swap(w0, w2);
      pl16_swap(w0, w2);
      pl32_swap(w1, w3);
      pl16_swap(w1, w3);
      int4 bw = make_int4((int)w0, (int)w1, (int)w2, (int)w3);
      short8v pb = __builtin_bit_cast(short8v, bw);
#pragma unroll
      for (int j = 0; j < 4; j++)
        oacc[j] = __builtin_amdgcn_mfma_f32_16x16x32_bf16(vf[j][ks], pb, oacc[j], 0, 0, 0);
    }
  }

  // epilogue: normalize + gate per lane, LDS transpose, coalesced store
  const int b = bh >> 4, h = bh & 15;
  const float g = gates[((size_t)(b * NN + q0 + lq)) * NH + h];
  const float sc = g / l_run;
  __shared__ float ots[4][16][68];
#pragma unroll
  for (int j = 0; j < 4; j++)
#pragma unroll
    for (int r = 0; r < 4; r++) ots[wid][lq][j * 16 + lg * 4 + r] = oacc[j][r] * sc;
  __syncthreads();
  const int qq = lane >> 2, d0 = (lane & 3) * 16;
  float* aor = ao + ((size_t)(b * NN + q0 + qq)) * DI + h * HD + d0;
#pragma unroll
  for (int u = 0; u < 4; u++) {
    float4 o = make_float4(ots[wid][qq][d0 + 4 * u + 0], ots[wid][qq][d0 + 4 * u + 1],
                           ots[wid][qq][d0 + 4 * u + 2], ots[wid][qq][d0 + 4 * u + 3]);
    *(float4*)(aor + 4 * u) = o;
  }
}

extern "C" void kernel_launch(void* const* d_in, const int* in_sizes, int n_in,
                              void* d_out, int out_size, void* d_ws, size_t ws_size,
                              hipStream_t stream) {
  const float* tokens = (const float*)d_in[0];
  const float* norm_w = (const float*)d_in[1];
  const float* Wq     = (const float*)d_in[2];
  const float* Wkv    = (const float*)d_in[3];
  const float* Wout   = (const float*)d_in[4];
  const float* Wg     = (const float*)d_in[5];
  float* out = (float*)d_out;

  float* ws = (float*)d_ws;
  float* x  = ws;                         // [4096][1024] f32
  float* ao = x + (size_t)MT * DM;        // [4096][1024] f32 gated attn out
  float* gb = ao + (size_t)MT * DM;       // [4096][16]   f32
  __hip_bfloat16* Qb  = (__hip_bfloat16*)(gb + (size_t)MT * NH);  // [32][2048][64]
  __hip_bfloat16* Kb  = Qb + (size_t)MT * DI;                     // [32][2048][64]
  __hip_bfloat16* Vtb = Kb + (size_t)MT * DI;                     // [32][64][2048]

  k_rmsnorm<<<MT, 256, 0, stream>>>(tokens, norm_w, x);
  k_gemm_t<1><<<dim3(DI / 64, MT / 64), 256, 0, stream>>>(x, Wq, nullptr, Qb, nullptr, DI);
  k_gemm_t<2><<<dim3(2 * DI / 64, MT / 64), 256, 0, stream>>>(x, Wkv, nullptr, Kb, Vtb, 2 * DI);
  k_gates<<<MT / 16, 256, 0, stream>>>(x, Wg, gb);
  k_attn_mfma<<<dim3(NN / 64, BB * NH), 256, 0, stream>>>(Qb, Kb, Vtb, gb, ao);
  k_gemm_t<0><<<dim3(DM / 64, MT / 64), 256, 0, stream>>>(ao, Wout, out, nullptr, nullptr, DM);
}

// Round 3
// 343.425 us; speedup vs baseline: 2.8679x; 2.1307x over previous
//
#include <hip/hip_runtime.h>
#include <hip/hip_bf16.h>
#include <math.h>

// ---- problem constants ----
constexpr int BB = 2;          // batch
constexpr int NN = 2048;       // seq len
constexpr int DM = 1024;       // model dim
constexpr int NH = 16;         // heads
constexpr int HD = 64;         // head dim
constexpr int DI = NH * HD;    // inner dim = 1024
constexpr int MT = BB * NN;    // 4096 tokens
constexpr float SM_SCALE = 0.125f * 1.44269504089f;  // 64^-0.5 * log2(e)

typedef __attribute__((ext_vector_type(8))) short short8v;  // 8 bf16 (4 VGPRs)
typedef __attribute__((ext_vector_type(4))) float f32x4;    // MFMA C/D

__device__ inline unsigned cvt_pk_bf16(float lo, float hi) {
  unsigned r;
  asm("v_cvt_pk_bf16_f32 %0, %1, %2" : "=v"(r) : "v"(lo), "v"(hi));
  return r;
}
__device__ inline void pl32_swap(unsigned& a, unsigned& b) {
  asm("v_permlane32_swap_b32 %0, %1" : "+v"(a), "+v"(b));
}
__device__ inline void pl16_swap(unsigned& a, unsigned& b) {
  asm("v_permlane16_swap_b32 %0, %1" : "+v"(a), "+v"(b));
}
__device__ __forceinline__ void gload16(const void* g, void* l) {
  __builtin_amdgcn_global_load_lds(
      (const __attribute__((address_space(1))) unsigned int*)g,
      (__attribute__((address_space(3))) unsigned int*)l, 16, 0, 0);
}

// ---------------- RMSNorm -> fp32 x (for gates) + bf16 xb (for MFMA GEMMs) ----
__global__ __launch_bounds__(256) void k_rmsnorm(const float* __restrict__ tokens,
                                                 const float* __restrict__ w,
                                                 float* __restrict__ x,
                                                 __hip_bfloat16* __restrict__ xb) {
  const int tok = blockIdx.x;
  const int t = threadIdx.x;
  float4 v = ((const float4*)(tokens + (size_t)tok * DM))[t];
  float ss = v.x * v.x + v.y * v.y + v.z * v.z + v.w * v.w;
#pragma unroll
  for (int m = 1; m < 64; m <<= 1) ss += __shfl_xor(ss, m, 64);
  __shared__ float red[4];
  if ((t & 63) == 0) red[t >> 6] = ss;
  __syncthreads();
  float tot = red[0] + red[1] + red[2] + red[3];
  float inv = rsqrtf(tot * (1.0f / DM) + 1.1920929e-7f);
  float4 wv = ((const float4*)w)[t];
  float4 o;
  o.x = v.x * inv * wv.x;
  o.y = v.y * inv * wv.y;
  o.z = v.z * inv * wv.z;
  o.w = v.w * inv * wv.w;
  ((float4*)(x + (size_t)tok * DM))[t] = o;
  uint2 pk = make_uint2(cvt_pk_bf16(o.x, o.y), cvt_pk_bf16(o.z, o.w));
  *(uint2*)(xb + (size_t)tok * DM + t * 4) = pk;
}

// ---------------- weight convert+transpose: W fp32 [K=1024][N] -> Wt bf16 [N][1024] ----
__global__ __launch_bounds__(256) void k_wtrans(const float* __restrict__ W,
                                                __hip_bfloat16* __restrict__ Wt, int N) {
  __shared__ float tile[32][33];
  const int t = threadIdx.x;
  const int c = t & 31, r8 = t >> 5;
  const int kb = blockIdx.y * 32, nb = blockIdx.x * 32;
#pragma unroll
  for (int i = 0; i < 4; i++)
    tile[r8 + i * 8][c] = W[(size_t)(kb + r8 + i * 8) * N + nb + c];
  __syncthreads();
#pragma unroll
  for (int i = 0; i < 4; i++)
    Wt[(size_t)(nb + r8 + i * 8) * DM + kb + c] = __float2bfloat16(tile[c][r8 + i * 8]);
}

// ---------------- bf16 MFMA GEMM (m97 structure): C[M][Nc] = A[M][1024] @ Bt[Nc][1024]^T
// BM=128, BN=64, BK=32, 4 waves (2x2), global_load_lds width-16 staging.
// MODE 0: fp32 C.  MODE 1: bf16 [b,h,n,d] into OK.  MODE 2: KV — cols<DI -> OK
// like MODE1; cols>=DI -> bf16 transposed [b,h,d,n] into OV.
template <int MODE>
__global__ __launch_bounds__(256) void k_mgemm(const __hip_bfloat16* __restrict__ A,
                                               const __hip_bfloat16* __restrict__ Bt,
                                               float* __restrict__ C,
                                               __hip_bfloat16* __restrict__ OK,
                                               __hip_bfloat16* __restrict__ OV, int Nc) {
  __shared__ __hip_bfloat16 As[128][32];  // 8 KB
  __shared__ __hip_bfloat16 Bs[64][32];   // 4 KB
  const int t = threadIdx.x, wid = t >> 6, lane = t & 63;
  const int lq = lane & 15, lg = lane >> 4;
  const int wr = wid >> 1, wc = wid & 1;
  const int m0 = blockIdx.y * 128, n0 = blockIdx.x * 64;
  const int srow = lane >> 2, scol = (lane & 3) * 8;

  const __hip_bfloat16* Ag = A + (size_t)(m0 + wid * 32 + srow) * DM + scol;
  const __hip_bfloat16* Bg = Bt + (size_t)(n0 + wid * 16 + srow) * DM + scol;

  f32x4 acc[4][2];
#pragma unroll
  for (int i = 0; i < 4; i++)
#pragma unroll
    for (int j = 0; j < 2; j++) acc[i][j] = (f32x4){0.f, 0.f, 0.f, 0.f};

  for (int k0 = 0; k0 < DM; k0 += 32) {
    __syncthreads();
    gload16(Ag + k0, &As[wid * 32][0]);
    gload16(Ag + 16 * DM + k0, &As[wid * 32 + 16][0]);
    gload16(Bg + k0, &Bs[wid * 16][0]);
    __syncthreads();
    short8v af[4], bf[2];
#pragma unroll
    for (int i = 0; i < 4; i++) af[i] = *(const short8v*)&As[wr * 64 + i * 16 + lq][lg * 8];
#pragma unroll
    for (int j = 0; j < 2; j++) bf[j] = *(const short8v*)&Bs[wc * 32 + j * 16 + lq][lg * 8];
#pragma unroll
    for (int i = 0; i < 4; i++)
#pragma unroll
      for (int j = 0; j < 2; j++)
        acc[i][j] = __builtin_amdgcn_mfma_f32_16x16x32_bf16(af[i], bf[j], acc[i][j], 0, 0, 0);
  }

  // epilogue: D[m][c], m = m0+wr*64+i*16+lg*4+r, c = n0+wc*32+j*16+lq
#pragma unroll
  for (int i = 0; i < 4; i++) {
    const int mb = m0 + wr * 64 + i * 16 + lg * 4;
#pragma unroll
    for (int j = 0; j < 2; j++) {
      const int c = n0 + wc * 32 + j * 16 + lq;
      if (MODE == 0) {
#pragma unroll
        for (int r = 0; r < 4; r++) C[(size_t)(mb + r) * Nc + c] = acc[i][j][r];
      } else if (MODE == 1 || (MODE == 2 && c < DI)) {
        const int b = mb >> 11, nl = mb & (NN - 1);
        const int h = (c & (DI - 1)) >> 6, d = c & 63;
        __hip_bfloat16* dst = OK + ((size_t)(b * NH + h) * NN + nl) * HD + d;
#pragma unroll
        for (int r = 0; r < 4; r++) dst[(size_t)r * HD] = __float2bfloat16(acc[i][j][r]);
      } else {
        const int cd = c - DI;
        const int b = mb >> 11, nl = mb & (NN - 1);
        const int h = cd >> 6, d = cd & 63;
        uint2 pk = make_uint2(cvt_pk_bf16(acc[i][j][0], acc[i][j][1]),
                              cvt_pk_bf16(acc[i][j][2], acc[i][j][3]));
        *(uint2*)(OV + ((size_t)(b * NH + h) * HD + d) * NN + nl) = pk;
      }
    }
  }
}

// ---------------- gates = sigmoid(x @ Wg) ----------------
__global__ __launch_bounds__(256) void k_gates(const float* __restrict__ x,
                                               const float* __restrict__ Wg,
                                               float* __restrict__ g) {
  const int tok = blockIdx.x * 16 + (threadIdx.x >> 4);
  const int h = threadIdx.x & 15;
  const float* xr = x + (size_t)tok * DM;
  float s = 0.f;
  for (int k = 0; k < DM; k += 4) {
    float4 xv = *(const float4*)(xr + k);
    s += xv.x * Wg[(k + 0) * NH + h];
    s += xv.y * Wg[(k + 1) * NH + h];
    s += xv.z * Wg[(k + 2) * NH + h];
    s += xv.w * Wg[(k + 3) * NH + h];
  }
  g[(size_t)tok * NH + h] = 1.f / (1.f + __expf(-s));
}

// ---------------- bf16 MFMA flash attention (unchanged structure; bf16 out) ----
__global__ __launch_bounds__(256) void k_attn_mfma(const __hip_bfloat16* __restrict__ Qb,
                                                   const __hip_bfloat16* __restrict__ Kb,
                                                   const __hip_bfloat16* __restrict__ Vtb,
                                                   const float* __restrict__ gates,
                                                   __hip_bfloat16* __restrict__ aob) {
  const int bh = blockIdx.y;
  const int qt = (int)gridDim.x - 1 - (int)blockIdx.x;
  const int wid = threadIdx.x >> 6;
  const int lane = threadIdx.x & 63;
  const int lg = lane >> 4, lq = lane & 15;
  const int q0 = qt * 64 + wid * 16;

  const __hip_bfloat16* Qh = Qb + (size_t)bh * NN * HD;
  const __hip_bfloat16* Kh = Kb + (size_t)bh * NN * HD;
  const __hip_bfloat16* Vh = Vtb + (size_t)bh * HD * NN;

  short8v qf[2];
#pragma unroll
  for (int ks = 0; ks < 2; ks++)
    qf[ks] = *(const short8v*)(Qh + (size_t)(q0 + lq) * HD + ks * 32 + lg * 8);

  f32x4 oacc[4];
#pragma unroll
  for (int j = 0; j < 4; j++) oacc[j] = (f32x4){0.f, 0.f, 0.f, 0.f};
  float m_run = -3.0e38f, l_run = 0.f;

  const int ntiles = qt + 1;
  for (int kt = 0; kt < ntiles; kt++) {
    const int kvb = kt * 64;
    short8v kf[4][2], vf[4][2];
#pragma unroll
    for (int j = 0; j < 4; j++)
#pragma unroll
      for (int ks = 0; ks < 2; ks++)
        kf[j][ks] = *(const short8v*)(Kh + (size_t)(kvb + j * 16 + lq) * HD + ks * 32 + lg * 8);
#pragma unroll
    for (int j = 0; j < 4; j++)
#pragma unroll
      for (int ks = 0; ks < 2; ks++)
        vf[j][ks] = *(const short8v*)(Vh + (size_t)(j * 16 + lq) * NN + kvb + ks * 32 + lg * 8);

    f32x4 sacc[4];
#pragma unroll
    for (int j = 0; j < 4; j++) sacc[j] = (f32x4){0.f, 0.f, 0.f, 0.f};
#pragma unroll
    for (int j = 0; j < 4; j++)
#pragma unroll
      for (int ks = 0; ks < 2; ks++)
        sacc[j] = __builtin_amdgcn_mfma_f32_16x16x32_bf16(kf[j][ks], qf[ks], sacc[j], 0, 0, 0);

    const int qg = q0 + lq;
    const bool diag = (kt == ntiles - 1);
    float ss[4][4];
#pragma unroll
    for (int j = 0; j < 4; j++)
#pragma unroll
      for (int r = 0; r < 4; r++) {
        float v = sacc[j][r] * SM_SCALE;
        if (diag && (kvb + j * 16 + lg * 4 + r > qg)) v = -3.0e38f;
        ss[j][r] = v;
      }

    float tmax = -3.0e38f;
#pragma unroll
    for (int j = 0; j < 4; j++)
#pragma unroll
      for (int r = 0; r < 4; r++) tmax = fmaxf(tmax, ss[j][r]);
    tmax = fmaxf(tmax, __shfl_xor(tmax, 16));
    tmax = fmaxf(tmax, __shfl_xor(tmax, 32));
    const float mnew = fmaxf(m_run, tmax);
    const float cf = exp2f(m_run - mnew);
    float psum = 0.f;
    unsigned upk[4], vpk[4];
#pragma unroll
    for (int j = 0; j < 4; j++) {
      float p0 = exp2f(ss[j][0] - mnew), p1 = exp2f(ss[j][1] - mnew);
      float p2 = exp2f(ss[j][2] - mnew), p3 = exp2f(ss[j][3] - mnew);
      psum += (p0 + p1) + (p2 + p3);
      upk[j] = cvt_pk_bf16(p0, p1);
      vpk[j] = cvt_pk_bf16(p2, p3);
    }
    psum += __shfl_xor(psum, 16);
    psum += __shfl_xor(psum, 32);
    l_run = l_run * cf + psum;
    m_run = mnew;
#pragma unroll
    for (int j = 0; j < 4; j++)
#pragma unroll
      for (int r = 0; r < 4; r++) oacc[j][r] *= cf;

#pragma unroll
    for (int ks = 0; ks < 2; ks++) {
      unsigned w0 = upk[2 * ks], w2 = upk[2 * ks + 1];
      unsigned w1 = vpk[2 * ks], w3 = vpk[2 * ks + 1];
      pl32_swap(w0, w2);
      pl16_swap(w0, w2);
      pl32_swap(w1, w3);
      pl16_swap(w1, w3);
      int4 bw = make_int4((int)w0, (int)w1, (int)w2, (int)w3);
      short8v pb = __builtin_bit_cast(short8v, bw);
#pragma unroll
      for (int j = 0; j < 4; j++)
        oacc[j] = __builtin_amdgcn_mfma_f32_16x16x32_bf16(vf[j][ks], pb, oacc[j], 0, 0, 0);
    }
  }

  const int b = bh >> 4, h = bh & 15;
  const float g = gates[((size_t)(b * NN + q0 + lq)) * NH + h];
  const float sc = g / l_run;
  __shared__ float ots[4][16][68];
#pragma unroll
  for (int j = 0; j < 4; j++)
#pragma unroll
    for (int r = 0; r < 4; r++) ots[wid][lq][j * 16 + lg * 4 + r] = oacc[j][r] * sc;
  __syncthreads();
  const int qq = lane >> 2, d0 = (lane & 3) * 16;
  __hip_bfloat16* aor = aob + ((size_t)(b * NN + q0 + qq)) * DI + h * HD + d0;
#pragma unroll
  for (int u = 0; u < 4; u++) {
    uint2 pk = make_uint2(
        cvt_pk_bf16(ots[wid][qq][d0 + 4 * u + 0], ots[wid][qq][d0 + 4 * u + 1]),
        cvt_pk_bf16(ots[wid][qq][d0 + 4 * u + 2], ots[wid][qq][d0 + 4 * u + 3]));
    *(uint2*)(aor + 4 * u) = pk;
  }
}

extern "C" void kernel_launch(void* const* d_in, const int* in_sizes, int n_in,
                              void* d_out, int out_size, void* d_ws, size_t ws_size,
                              hipStream_t stream) {
  const float* tokens = (const float*)d_in[0];
  const float* norm_w = (const float*)d_in[1];
  const float* Wq     = (const float*)d_in[2];
  const float* Wkv    = (const float*)d_in[3];
  const float* Wout   = (const float*)d_in[4];
  const float* Wg     = (const float*)d_in[5];
  float* out = (float*)d_out;

  float* ws = (float*)d_ws;
  float* x  = ws;                          // [4096][1024] f32
  float* gb = x + (size_t)MT * DM;         // [4096][16]   f32
  __hip_bfloat16* xb   = (__hip_bfloat16*)(gb + (size_t)MT * NH);  // [4096][1024]
  __hip_bfloat16* aob  = xb + (size_t)MT * DM;                     // [4096][1024]
  __hip_bfloat16* Qb   = aob + (size_t)MT * DM;                    // [32][2048][64]
  __hip_bfloat16* Kb   = Qb + (size_t)MT * DI;                     // [32][2048][64]
  __hip_bfloat16* Vtb  = Kb + (size_t)MT * DI;                     // [32][64][2048]
  __hip_bfloat16* Wqt  = Vtb + (size_t)MT * DI;                    // [1024][1024]
  __hip_bfloat16* Wkvt = Wqt + (size_t)DI * DM;                    // [2048][1024]
  __hip_bfloat16* Woutt= Wkvt + (size_t)2 * DI * DM;               // [1024][1024]

  k_rmsnorm<<<MT, 256, 0, stream>>>(tokens, norm_w, x, xb);
  k_wtrans<<<dim3(DI / 32, DM / 32), 256, 0, stream>>>(Wq, Wqt, DI);
  k_wtrans<<<dim3(2 * DI / 32, DM / 32), 256, 0, stream>>>(Wkv, Wkvt, 2 * DI);
  k_wtrans<<<dim3(DM / 32, DI / 32), 256, 0, stream>>>(Wout, Woutt, DM);
  k_gates<<<MT / 16, 256, 0, stream>>>(x, Wg, gb);
  k_mgemm<1><<<dim3(DI / 64, MT / 128), 256, 0, stream>>>(xb, Wqt, nullptr, Qb, nullptr, DI);
  k_mgemm<2><<<dim3(2 * DI / 64, MT / 128), 256, 0, stream>>>(xb, Wkvt, nullptr, Kb, Vtb, 2 * DI);
  k_attn_mfma<<<dim3(NN / 64, BB * NH), 256, 0, stream>>>(Qb, Kb, Vtb, gb, aob);
  k_mgemm<0><<<dim3(DM / 64, MT / 128), 256, 0, stream>>>(aob, Woutt, out, nullptr, nullptr, DM);
}